// Round 2
// baseline (171.384 us; speedup 1.0000x reference)
//
#include <hip/hip_runtime.h>
#include <stdint.h>

#define N_ROWS 8192
#define DDIM   512

typedef __bf16 bf16_t;
typedef bf16_t bf16x8 __attribute__((ext_vector_type(8)));
typedef float  f32x4  __attribute__((ext_vector_type(4)));

// ---------------- f32 -> bf16 (RNE) convert, vectorized ----------------
__device__ inline uint16_t f2bf(float f) {
    uint32_t u = __float_as_uint(f);
    u += 0x7FFFu + ((u >> 16) & 1u);
    return (uint16_t)(u >> 16);
}

__global__ void convert_bf16(const float* __restrict__ a, const float* __restrict__ b,
                             uint16_t* __restrict__ abf, uint16_t* __restrict__ bbf) {
    const int quads = N_ROWS * DDIM / 4;
    const int stride = gridDim.x * blockDim.x;
    for (int i = blockIdx.x * blockDim.x + threadIdx.x; i < quads; i += stride) {
        float4 va = ((const float4*)a)[i];
        float4 vb = ((const float4*)b)[i];
        ushort4 ra, rb;
        ra.x = f2bf(va.x); ra.y = f2bf(va.y); ra.z = f2bf(va.z); ra.w = f2bf(va.w);
        rb.x = f2bf(vb.x); rb.y = f2bf(vb.y); rb.z = f2bf(vb.z); rb.w = f2bf(vb.w);
        ((ushort4*)abf)[i] = ra;
        ((ushort4*)bbf)[i] = rb;
    }
}

// ---------------- async global->LDS 16B stage ----------------
// LDS dest is wave-uniform base + lane*16 (HW-fixed); global source is per-lane.
__device__ inline void stage16(const uint8_t* g, uint8_t* lds_wave_base) {
#if __has_builtin(__builtin_amdgcn_global_load_lds)
    __builtin_amdgcn_global_load_lds(
        (const __attribute__((address_space(1))) uint32_t*)g,
        (__attribute__((address_space(3))) uint32_t*)lds_wave_base, 16, 0, 0);
#else
    *(int4*)(lds_wave_base) = *(const int4*)g;
#endif
}

// ---------------- fused GEMM + exp-accumulate ----------------
// Fragment-major LDS layout: stripe s (1 KB) holds rows s*16..s*16+15 of the
// tile; granule `lane` within a stripe = (row s*16+(lane&15), k-slot lane>>4).
// Every MFMA fragment ds_read_b128 is then `stripe_base + lane*16`:
// contiguous, lane-ordered, zero bank conflicts.
__global__ void __launch_bounds__(256)
clip_gemm(const uint16_t* __restrict__ A, const uint16_t* __restrict__ B,
          const float* __restrict__ scale_p,
          float* __restrict__ rowsum, float* __restrict__ colsum,
          float* __restrict__ diag) {
    __shared__ __attribute__((aligned(16))) uint8_t As[128 * 64];  // 8 stripes x 1KB
    __shared__ __attribute__((aligned(16))) uint8_t Bs[128 * 64];

    const int t    = threadIdx.x;
    const int wave = t >> 6;
    const int lane = t & 63;
    const int wr   = wave >> 1;   // 0..1 : wave row
    const int wc   = wave & 1;    // 0..1 : wave col

    // XCD-aware band swizzle: xcd = lin&7 owns bm-band [xcd*8, xcd*8+8),
    // sweeping bn. Keeps a 1 MB A-band L2-resident per XCD. Bijective.
    const int lin = blockIdx.x;        // 0..4095
    const int idx = lin >> 3;          // 0..511
    const int bm  = ((lin & 7) << 3) | (idx & 7);
    const int bn  = idx >> 3;

    const float s     = *scale_p;
    const float shift = s - 64.0f;

    f32x4 acc[4][4];
#pragma unroll
    for (int m = 0; m < 4; ++m)
#pragma unroll
        for (int n = 0; n < 4; ++n)
#pragma unroll
            for (int r = 0; r < 4; ++r) acc[m][n][r] = 0.0f;

    // staging source (fragment-major): wave w stages stripe w (rows w*16+lr)
    // call 1, stripe w+4 (rows 64+w*16+lr) call 2. Lane supplies
    // row = stripe*16 + (lane&15), k-bytes (lane>>4)*16.
    const size_t rowbytes = (size_t)DDIM * 2;
    const uint8_t* Ag = (const uint8_t*)A
        + (size_t)(bm * 128 + wave * 16 + (lane & 15)) * rowbytes + (size_t)(lane >> 4) * 16;
    const uint8_t* Bg = (const uint8_t*)B
        + (size_t)(bn * 128 + wave * 16 + (lane & 15)) * rowbytes + (size_t)(lane >> 4) * 16;
    const size_t rowskip = (size_t)64 * rowbytes;

    uint8_t* AsW = As + wave * 1024;
    uint8_t* BsW = Bs + wave * 1024;

    const int lr = lane & 15;         // fragment row/col
    const int lg = lane >> 4;         // 0..3 (k-slot)

    for (int k0 = 0; k0 < DDIM; k0 += 32) {
        __syncthreads();              // previous compute done before overwrite
        const size_t kb = (size_t)k0 * 2;
        stage16(Ag + kb,           AsW);
        stage16(Ag + kb + rowskip, AsW + 4096);
        stage16(Bg + kb,           BsW);
        stage16(Bg + kb + rowskip, BsW + 4096);
        __syncthreads();              // drains vmcnt: tile resident

        bf16x8 a[4], b[4];
#pragma unroll
        for (int m = 0; m < 4; ++m)
            a[m] = *(const bf16x8*)(As + (wr * 4 + m) * 1024 + lane * 16);
#pragma unroll
        for (int n = 0; n < 4; ++n)
            b[n] = *(const bf16x8*)(Bs + (wc * 4 + n) * 1024 + lane * 16);
#pragma unroll
        for (int m = 0; m < 4; ++m)
#pragma unroll
            for (int n = 0; n < 4; ++n)
                acc[m][n] = __builtin_amdgcn_mfma_f32_16x16x32_bf16(a[m], b[n], acc[m][n], 0, 0, 0);
    }

    // ---------------- epilogue: exp + reductions ----------------
    // D layout: col = lane&15, row = (lane>>4)*4 + reg
    float rpart[4][4];
    float cpart[4] = {0.f, 0.f, 0.f, 0.f};
#pragma unroll
    for (int m = 0; m < 4; ++m)
#pragma unroll
        for (int r = 0; r < 4; ++r) rpart[m][r] = 0.f;

#pragma unroll
    for (int m = 0; m < 4; ++m) {
#pragma unroll
        for (int n = 0; n < 4; ++n) {
#pragma unroll
            for (int r = 0; r < 4; ++r) {
                const float logit = s * acc[m][n][r];
                const float e = __expf(logit - shift);
                rpart[m][r] += e;
                cpart[n]    += e;
                if (bm == bn && wr == wc && m == n && lr == lg * 4 + r)
                    diag[bm * 128 + wr * 64 + m * 16 + lr] = logit;
            }
        }
    }

    // row sums: reduce across 16 lanes sharing the same row (xor 1,2,4,8)
#pragma unroll
    for (int m = 0; m < 4; ++m) {
#pragma unroll
        for (int r = 0; r < 4; ++r) {
            float v = rpart[m][r];
            v += __shfl_xor(v, 1);
            v += __shfl_xor(v, 2);
            v += __shfl_xor(v, 4);
            v += __shfl_xor(v, 8);
            if (lr == 0)
                atomicAdd(&rowsum[bm * 128 + wr * 64 + m * 16 + lg * 4 + r], v);
        }
    }
    // col sums: reduce across the 4 lanes sharing the same col (xor 16,32)
#pragma unroll
    for (int n = 0; n < 4; ++n) {
        float v = cpart[n];
        v += __shfl_xor(v, 16);
        v += __shfl_xor(v, 32);
        if (lg == 0)
            atomicAdd(&colsum[bn * 128 + wc * 64 + n * 16 + lr], v);
    }
}

// ---------------- final reduce: loss scalar (parallel) ----------------
__global__ void clip_finalize(const float* __restrict__ rowsum, const float* __restrict__ colsum,
                              const float* __restrict__ diag, const float* __restrict__ scale_p,
                              float* __restrict__ out) {
    __shared__ float red[4];
    const float s = *scale_p;
    const float shift = s - 64.0f;
    const int i = blockIdx.x * 256 + threadIdx.x;   // grid 32 x 256 = 8192
    float acc = logf(rowsum[i]) + logf(colsum[i]) + 2.f * shift - 2.f * diag[i];
#pragma unroll
    for (int m = 1; m < 64; m <<= 1) acc += __shfl_xor(acc, m);
    const int wave = threadIdx.x >> 6;
    const int lane = threadIdx.x & 63;
    if (lane == 0) red[wave] = acc;
    __syncthreads();
    if (threadIdx.x == 0) {
        atomicAdd(out, (red[0] + red[1] + red[2] + red[3]) / (2.0f * N_ROWS));
    }
}

extern "C" void kernel_launch(void* const* d_in, const int* in_sizes, int n_in,
                              void* d_out, int out_size, void* d_ws, size_t ws_size,
                              hipStream_t stream) {
    const float* img     = (const float*)d_in[0];
    const float* txt     = (const float*)d_in[1];
    const float* scale_p = (const float*)d_in[2];

    uint8_t* ws = (uint8_t*)d_ws;
    uint16_t* Abf   = (uint16_t*)ws;                                  // 8 MB
    uint16_t* Bbf   = (uint16_t*)(ws + (size_t)8 * 1024 * 1024);      // 8 MB
    float*    rowsum = (float*)(ws + (size_t)16 * 1024 * 1024);       // 32 KB
    float*    colsum = rowsum + N_ROWS;                               // 32 KB
    float*    diag   = colsum + N_ROWS;                               // 32 KB
    float*    out    = (float*)d_out;

    hipMemsetAsync(rowsum, 0, 2 * N_ROWS * sizeof(float), stream);
    hipMemsetAsync(out, 0, sizeof(float), stream);
    convert_bf16<<<1024, 256, 0, stream>>>(img, txt, Abf, Bbf);
    clip_gemm<<<4096, 256, 0, stream>>>(Abf, Bbf, scale_p, rowsum, colsum, diag);
    clip_finalize<<<32, 256, 0, stream>>>(rowsum, colsum, diag, scale_p, out);
}

// Round 3
// 127.459 us; speedup vs baseline: 1.3446x; 1.3446x over previous
//
#include <hip/hip_runtime.h>
#include <stdint.h>

#define N_ROWS 8192
#define DDIM   512

typedef __bf16 bf16_t;
typedef bf16_t bf16x8 __attribute__((ext_vector_type(8)));
typedef float  f32x4  __attribute__((ext_vector_type(4)));

// ---------------- f32 -> bf16 (RNE) convert, vectorized ----------------
__device__ inline uint16_t f2bf(float f) {
    uint32_t u = __float_as_uint(f);
    u += 0x7FFFu + ((u >> 16) & 1u);
    return (uint16_t)(u >> 16);
}

__global__ void convert_bf16(const float* __restrict__ a, const float* __restrict__ b,
                             uint16_t* __restrict__ abf, uint16_t* __restrict__ bbf) {
    const int quads = N_ROWS * DDIM / 4;
    const int stride = gridDim.x * blockDim.x;
    for (int i = blockIdx.x * blockDim.x + threadIdx.x; i < quads; i += stride) {
        float4 va = ((const float4*)a)[i];
        float4 vb = ((const float4*)b)[i];
        ushort4 ra, rb;
        ra.x = f2bf(va.x); ra.y = f2bf(va.y); ra.z = f2bf(va.z); ra.w = f2bf(va.w);
        rb.x = f2bf(vb.x); rb.y = f2bf(vb.y); rb.z = f2bf(vb.z); rb.w = f2bf(vb.w);
        ((ushort4*)abf)[i] = ra;
        ((ushort4*)bbf)[i] = rb;
    }
}

// ---------------- async global->LDS 16B stage ----------------
__device__ inline void stage16(const uint8_t* g, uint8_t* lds_wave_base) {
#if __has_builtin(__builtin_amdgcn_global_load_lds)
    __builtin_amdgcn_global_load_lds(
        (const __attribute__((address_space(1))) uint32_t*)g,
        (__attribute__((address_space(3))) uint32_t*)lds_wave_base, 16, 0, 0);
#else
    *(int4*)(lds_wave_base) = *(const int4*)g;
#endif
}

// ---------------- fused GEMM + exp-accumulate ----------------
// LDS layout = row-major [128 rows][64B k-window] with an XOR micro-swizzle
// WITHIN each row's 64B: chunk c of row r holds k-slot c^(r&3).
// * Staging source: lane t reads row t>>2, chunk ((t&3)^((t>>2)&3))*16 —
//   each 4-lane quad still covers one contiguous 64B line (coalescing kept).
// * Fragment read: addr = row*64 + ((lane>>4)^(lane&3))*16 — 2 lanes/bank-slot
//   = 2-way conflict = free (m136).
__global__ void __launch_bounds__(256)
clip_gemm(const uint16_t* __restrict__ A, const uint16_t* __restrict__ B,
          const float* __restrict__ scale_p,
          float* __restrict__ rowsum, float* __restrict__ colsum,
          float* __restrict__ diag) {
    __shared__ __attribute__((aligned(16))) uint8_t As[128 * 64];
    __shared__ __attribute__((aligned(16))) uint8_t Bs[128 * 64];

    const int t    = threadIdx.x;
    const int wave = t >> 6;
    const int lane = t & 63;
    const int wr   = wave >> 1;   // 0..1 : wave row
    const int wc   = wave & 1;    // 0..1 : wave col
    const int bm   = blockIdx.x;
    const int bn   = blockIdx.y;

    const float s     = *scale_p;
    const float shift = s - 64.0f;

    f32x4 acc[4][4];
#pragma unroll
    for (int m = 0; m < 4; ++m)
#pragma unroll
        for (int n = 0; n < 4; ++n)
#pragma unroll
            for (int r = 0; r < 4; ++r) acc[m][n][r] = 0.0f;

    // staging source: row = bm*128 + t>>2 (same as R1), chunk XOR-permuted
    // within the row's 64B line.
    const size_t rowbytes = (size_t)DDIM * 2;
    const int    kchunk   = ((t & 3) ^ ((t >> 2) & 3)) * 16;
    const uint8_t* Ag = (const uint8_t*)A + (size_t)(bm * 128 + (t >> 2)) * rowbytes + kchunk;
    const uint8_t* Bg = (const uint8_t*)B + (size_t)(bn * 128 + (t >> 2)) * rowbytes + kchunk;
    const size_t rowskip = (size_t)64 * rowbytes;

    uint8_t* AsW = As + wave * 1024;
    uint8_t* BsW = Bs + wave * 1024;

    const int lr = lane & 15;                         // fragment row/col
    const int lg = lane >> 4;                         // k-slot 0..3
    // swizzled chunk offset for fragment reads (row&3 == lr&3 == lane&3):
    const int rq = ((lg ^ (lane & 3)) * 16);

    for (int k0 = 0; k0 < DDIM; k0 += 32) {
        __syncthreads();              // previous compute done before overwrite
        const size_t kb = (size_t)k0 * 2;
        stage16(Ag + kb,           AsW);
        stage16(Ag + kb + rowskip, AsW + 4096);
        stage16(Bg + kb,           BsW);
        stage16(Bg + kb + rowskip, BsW + 4096);
        __syncthreads();              // drains vmcnt: tile resident

        bf16x8 a[4], b[4];
#pragma unroll
        for (int m = 0; m < 4; ++m)
            a[m] = *(const bf16x8*)(As + (wr * 64 + m * 16 + lr) * 64 + rq);
#pragma unroll
        for (int n = 0; n < 4; ++n)
            b[n] = *(const bf16x8*)(Bs + (wc * 64 + n * 16 + lr) * 64 + rq);
#pragma unroll
        for (int m = 0; m < 4; ++m)
#pragma unroll
            for (int n = 0; n < 4; ++n)
                acc[m][n] = __builtin_amdgcn_mfma_f32_16x16x32_bf16(a[m], b[n], acc[m][n], 0, 0, 0);
    }

    // ---------------- epilogue: exp + reductions ----------------
    // D layout: col = lane&15, row = (lane>>4)*4 + reg
    float rpart[4][4];
    float cpart[4] = {0.f, 0.f, 0.f, 0.f};
#pragma unroll
    for (int m = 0; m < 4; ++m)
#pragma unroll
        for (int r = 0; r < 4; ++r) rpart[m][r] = 0.f;

#pragma unroll
    for (int m = 0; m < 4; ++m) {
#pragma unroll
        for (int n = 0; n < 4; ++n) {
#pragma unroll
            for (int r = 0; r < 4; ++r) {
                const float logit = s * acc[m][n][r];
                const float e = __expf(logit - shift);
                rpart[m][r] += e;
                cpart[n]    += e;
                if (bm == bn && wr == wc && m == n && lr == lg * 4 + r)
                    diag[bm * 128 + wr * 64 + m * 16 + lr] = logit;
            }
        }
    }

    // row sums: reduce across 16 lanes sharing the same row (xor 1,2,4,8)
#pragma unroll
    for (int m = 0; m < 4; ++m) {
#pragma unroll
        for (int r = 0; r < 4; ++r) {
            float v = rpart[m][r];
            v += __shfl_xor(v, 1);
            v += __shfl_xor(v, 2);
            v += __shfl_xor(v, 4);
            v += __shfl_xor(v, 8);
            if (lr == 0)
                atomicAdd(&rowsum[bm * 128 + wr * 64 + m * 16 + lg * 4 + r], v);
        }
    }
    // col sums: reduce across the 4 lanes sharing the same col (xor 16,32)
#pragma unroll
    for (int n = 0; n < 4; ++n) {
        float v = cpart[n];
        v += __shfl_xor(v, 16);
        v += __shfl_xor(v, 32);
        if (lg == 0)
            atomicAdd(&colsum[bn * 128 + wc * 64 + n * 16 + lr], v);
    }
}

// ---------------- final reduce: loss scalar (parallel) ----------------
__global__ void clip_finalize(const float* __restrict__ rowsum, const float* __restrict__ colsum,
                              const float* __restrict__ diag, const float* __restrict__ scale_p,
                              float* __restrict__ out) {
    __shared__ float red[4];
    const float s = *scale_p;
    const float shift = s - 64.0f;
    const int i = blockIdx.x * 256 + threadIdx.x;   // grid 32 x 256 = 8192
    float acc = logf(rowsum[i]) + logf(colsum[i]) + 2.f * shift - 2.f * diag[i];
#pragma unroll
    for (int m = 1; m < 64; m <<= 1) acc += __shfl_xor(acc, m);
    const int wave = threadIdx.x >> 6;
    const int lane = threadIdx.x & 63;
    if (lane == 0) red[wave] = acc;
    __syncthreads();
    if (threadIdx.x == 0) {
        atomicAdd(out, (red[0] + red[1] + red[2] + red[3]) / (2.0f * N_ROWS));
    }
}

extern "C" void kernel_launch(void* const* d_in, const int* in_sizes, int n_in,
                              void* d_out, int out_size, void* d_ws, size_t ws_size,
                              hipStream_t stream) {
    const float* img     = (const float*)d_in[0];
    const float* txt     = (const float*)d_in[1];
    const float* scale_p = (const float*)d_in[2];

    uint8_t* ws = (uint8_t*)d_ws;
    uint16_t* Abf   = (uint16_t*)ws;                                  // 8 MB
    uint16_t* Bbf   = (uint16_t*)(ws + (size_t)8 * 1024 * 1024);      // 8 MB
    float*    rowsum = (float*)(ws + (size_t)16 * 1024 * 1024);       // 32 KB
    float*    colsum = rowsum + N_ROWS;                               // 32 KB
    float*    diag   = colsum + N_ROWS;                               // 32 KB
    float*    out    = (float*)d_out;

    hipMemsetAsync(rowsum, 0, 2 * N_ROWS * sizeof(float), stream);
    hipMemsetAsync(out, 0, sizeof(float), stream);
    convert_bf16<<<1024, 256, 0, stream>>>(img, txt, Abf, Bbf);
    dim3 grid(64, 64);
    clip_gemm<<<grid, 256, 0, stream>>>(Abf, Bbf, scale_p, rowsum, colsum, diag);
    clip_finalize<<<32, 256, 0, stream>>>(rowsum, colsum, diag, scale_p, out);
}